// Round 6
// baseline (137.752 us; speedup 1.0000x reference)
//
#include <hip/hip_runtime.h>

// B=4, N=M=4096, D=3, fp32 (fixed by reference setup_inputs).
#define B_   4
#define N_   4096
#define BN_  (B_ * N_)          // 16384 points per cloud
#define TPB  256
#define PT   8                  // P-points per thread
#define QS   64                 // Q-slice staged in LDS per block
#define NBLK (2 * B_ * (N_ / QS) * (N_ / (PT * TPB)))   // 8*64*2 = 1024

// ws layout:
//   float4 packed[2][B][N] : (qx,qy,qz, 0.5*|q|^2)             512 KB
//   uint   mins  [2][B][N] : ordered-int-encoded running min   128 KB
//   uint   counter         : done-block count (last block finalizes)

__device__ __forceinline__ unsigned enc_ord(float f) {
    int b = __float_as_int(f);
    return (unsigned)(b ^ ((b >> 31) | 0x80000000));
}
__device__ __forceinline__ float dec_ord(unsigned u) {
    int b = (u & 0x80000000u) ? (int)(u ^ 0x80000000u) : ~(int)u;
    return __int_as_float(b);
}

__global__ __launch_bounds__(TPB) void pack_kernel(
    const float* __restrict__ x, const float* __restrict__ y,
    float4* __restrict__ pk, unsigned* __restrict__ mins,
    unsigned* __restrict__ counter)
{
    const int gid = blockIdx.x * TPB + threadIdx.x;   // [0, 2*BN)
    if (gid == 0) *counter = 0u;
    const float* src = (gid < BN_) ? x : y;
    const int idx = gid & (BN_ - 1);
    const float a0 = src[idx * 3 + 0];
    const float a1 = src[idx * 3 + 1];
    const float a2 = src[idx * 3 + 2];
    const float hqq = 0.5f * (a0 * a0 + a1 * a1 + a2 * a2);
    pk[gid] = make_float4(a0, a1, a2, hqq);
    mins[gid] = 0xFFFFFFFFu;                          // +inf in encoded order
}

// grid: (64 Q-slices of 64, 2 P-groups of 2048, 2B dirs) = 1024 blocks
// -> 4 blocks/CU, 16 waves/CU, 4 waves/SIMD. LDS broadcast ds_read_b128,
// 32 VALU per read. Last finished block performs the final reduction.
__global__ __launch_bounds__(TPB) void chamfer_kernel(
    const float4* __restrict__ pk, unsigned* __restrict__ mins,
    unsigned* __restrict__ counter, float* __restrict__ out)
{
    __shared__ float4 sQ[QS];

    const int z    = blockIdx.z;
    const int b    = z & (B_ - 1);
    const bool swp = z >= B_;
    const float4* pkP = pk + (swp ? BN_ : 0) + b * N_;
    const float4* pkQ = pk + (swp ? 0 : BN_) + b * N_;
    unsigned*    omin = mins + (swp ? BN_ : 0) + b * N_;

    const int tid = threadIdx.x;
    if (tid < QS) sQ[tid] = pkQ[blockIdx.x * QS + tid];

    const int n0 = blockIdx.y * (PT * TPB) + tid;
    float4 p[PT];
    float  m[PT];
    #pragma unroll
    for (int k = 0; k < PT; ++k) {
        p[k] = pkP[n0 + k * TPB];
        m[k] = 3.4e38f;
    }
    __syncthreads();

    #pragma unroll 8
    for (int j = 0; j < QS; ++j) {
        const float4 qq = sQ[j];                // ds_read_b128 broadcast
        #pragma unroll
        for (int k = 0; k < PT; ++k) {
            const float e = fmaf(-p[k].x, qq.x,
                            fmaf(-p[k].y, qq.y,
                            fmaf(-p[k].z, qq.z, qq.w)));
            m[k] = fminf(m[k], e);
        }
    }

    // d2 = pp + 2*e = 2*(e + 0.5pp); clamp deferred to finalize (monotone).
    #pragma unroll
    for (int k = 0; k < PT; ++k)
        atomicMin(&omin[n0 + k * TPB], enc_ord((m[k] + p[k].w) * 2.0f));

    // ---- last-block finalize ----
    __threadfence();                            // make our mins visible
    __syncthreads();                            // all threads' atomics issued
    __shared__ unsigned s_last;
    if (tid == 0) s_last = atomicAdd(counter, 1u);
    __syncthreads();
    if (s_last != NBLK - 1) return;

    float s0 = 0.0f, s1 = 0.0f;
    for (int i = tid; i < BN_; i += TPB) {      // 64 iters per half
        const unsigned a = __hip_atomic_load(&mins[i], __ATOMIC_RELAXED,
                                             __HIP_MEMORY_SCOPE_AGENT);
        const unsigned c = __hip_atomic_load(&mins[BN_ + i], __ATOMIC_RELAXED,
                                             __HIP_MEMORY_SCOPE_AGENT);
        s0 += fmaxf(dec_ord(a), 0.0f);
        s1 += fmaxf(dec_ord(c), 0.0f);
    }
    #pragma unroll
    for (int o = 32; o > 0; o >>= 1) {
        s0 += __shfl_down(s0, o);
        s1 += __shfl_down(s1, o);
    }
    __shared__ float w0[4], w1[4];
    const int w = tid >> 6;
    if ((tid & 63) == 0) { w0[w] = s0; w1[w] = s1; }
    __syncthreads();
    if (tid == 0) {
        const float t0 = w0[0] + w0[1] + w0[2] + w0[3];
        const float t1 = w1[0] + w1[1] + w1[2] + w1[3];
        const float inv = 1.0f / (float)BN_;
        out[0] = fmaxf(t0 * inv, t1 * inv);
    }
}

extern "C" void kernel_launch(void* const* d_in, const int* in_sizes, int n_in,
                              void* d_out, int out_size, void* d_ws, size_t ws_size,
                              hipStream_t stream)
{
    const float* x = (const float*)d_in[0];
    const float* y = (const float*)d_in[1];
    float* out = (float*)d_out;

    float4*   pk      = (float4*)d_ws;                 // 2*BN float4
    unsigned* mins    = (unsigned*)(pk + 2 * BN_);     // 2*BN uint
    unsigned* counter = mins + 2 * BN_;                // 1 uint

    pack_kernel<<<2 * BN_ / TPB, TPB, 0, stream>>>(x, y, pk, mins, counter);

    dim3 grid(N_ / QS, N_ / (PT * TPB), 2 * B_);       // 64 x 2 x 8 = 1024
    chamfer_kernel<<<grid, TPB, 0, stream>>>(pk, mins, counter, out);
}

// Round 7
// 72.025 us; speedup vs baseline: 1.9125x; 1.9125x over previous
//
#include <hip/hip_runtime.h>

// B=4, N=M=4096, D=3, fp32 (fixed by reference setup_inputs).
#define B_   4
#define N_   4096
#define BN_  (B_ * N_)          // 16384 points per cloud
#define TPB  256
#define PT   8                  // P-points per thread
#define QS   64                 // Q-slice staged in LDS per block

// ws layout:
//   float4 packed[2][B][N] : (qx,qy,qz, 0.5*|q|^2)             512 KB
//   uint   mins  [2][B][N] : ordered-int-encoded running min   128 KB
//
// NOTE (R6 lesson): do NOT fuse the finalize via __threadfence() — a
// device-scope release on gfx950 forces per-block L2 writeback/invalidate
// (non-coherent per-XCD L2s); 1024 of them serialized the machine
// (chamfer 18.5 -> 87 us, WRITE_SIZE 2 -> 8.2 MB). Kernel boundary is the
// free fence.

__device__ __forceinline__ unsigned enc_ord(float f) {
    int b = __float_as_int(f);
    return (unsigned)(b ^ ((b >> 31) | 0x80000000));
}
__device__ __forceinline__ float dec_ord(unsigned u) {
    int b = (u & 0x80000000u) ? (int)(u ^ 0x80000000u) : ~(int)u;
    return __int_as_float(b);
}

__global__ __launch_bounds__(TPB) void pack_kernel(
    const float* __restrict__ x, const float* __restrict__ y,
    float4* __restrict__ pk, unsigned* __restrict__ mins)
{
    const int gid = blockIdx.x * TPB + threadIdx.x;   // [0, 2*BN)
    const float* src = (gid < BN_) ? x : y;
    const int idx = gid & (BN_ - 1);
    const float a0 = src[idx * 3 + 0];
    const float a1 = src[idx * 3 + 1];
    const float a2 = src[idx * 3 + 2];
    const float hqq = 0.5f * (a0 * a0 + a1 * a1 + a2 * a2);
    pk[gid] = make_float4(a0, a1, a2, hqq);
    mins[gid] = 0xFFFFFFFFu;                          // +inf in encoded order
}

// grid: (64 Q-slices of 64, 2 P-groups of 2048, 2B dirs) = 1024 blocks
// -> 4 blocks/CU, 16 waves/CU, 4 waves/SIMD to hide ds_read latency.
// LDS broadcast ds_read_b128 (conflict-free), 32 VALU per read.
__global__ __launch_bounds__(TPB) void chamfer_kernel(
    const float4* __restrict__ pk, unsigned* __restrict__ mins)
{
    __shared__ float4 sQ[QS];

    const int z    = blockIdx.z;
    const int b    = z & (B_ - 1);
    const bool swp = z >= B_;
    const float4* pkP = pk + (swp ? BN_ : 0) + b * N_;
    const float4* pkQ = pk + (swp ? 0 : BN_) + b * N_;
    unsigned*    omin = mins + (swp ? BN_ : 0) + b * N_;

    const int tid = threadIdx.x;
    if (tid < QS) sQ[tid] = pkQ[blockIdx.x * QS + tid];

    const int n0 = blockIdx.y * (PT * TPB) + tid;
    float4 p[PT];
    float  m[PT];
    #pragma unroll
    for (int k = 0; k < PT; ++k) {
        p[k] = pkP[n0 + k * TPB];
        m[k] = 3.4e38f;
    }
    __syncthreads();

    #pragma unroll 8
    for (int j = 0; j < QS; ++j) {
        const float4 qq = sQ[j];                // ds_read_b128 broadcast
        #pragma unroll
        for (int k = 0; k < PT; ++k) {
            const float e = fmaf(-p[k].x, qq.x,
                            fmaf(-p[k].y, qq.y,
                            fmaf(-p[k].z, qq.z, qq.w)));
            m[k] = fminf(m[k], e);
        }
    }

    // d2 = pp + 2*e = 2*(e + 0.5pp); clamp deferred to finalize (monotone).
    #pragma unroll
    for (int k = 0; k < PT; ++k)
        atomicMin(&omin[n0 + k * TPB], enc_ord((m[k] + p[k].w) * 2.0f));
}

__global__ __launch_bounds__(1024) void finalize_kernel(
    const unsigned* __restrict__ mins, float* __restrict__ out)
{
    const int tid = threadIdx.x;
    const uint4* m4 = (const uint4*)mins;       // 8192 uint4 total
    float s0 = 0.0f, s1 = 0.0f;
    #pragma unroll
    for (int i = 0; i < BN_ / 4; i += 1024) {   // 4 iters per half
        const uint4 a = m4[i + tid];
        s0 += fmaxf(dec_ord(a.x), 0.0f) + fmaxf(dec_ord(a.y), 0.0f)
            + fmaxf(dec_ord(a.z), 0.0f) + fmaxf(dec_ord(a.w), 0.0f);
        const uint4 c = m4[BN_ / 4 + i + tid];
        s1 += fmaxf(dec_ord(c.x), 0.0f) + fmaxf(dec_ord(c.y), 0.0f)
            + fmaxf(dec_ord(c.z), 0.0f) + fmaxf(dec_ord(c.w), 0.0f);
    }
    #pragma unroll
    for (int o = 32; o > 0; o >>= 1) {
        s0 += __shfl_down(s0, o);
        s1 += __shfl_down(s1, o);
    }
    __shared__ float w0[16], w1[16];
    const int w = tid >> 6;
    if ((tid & 63) == 0) { w0[w] = s0; w1[w] = s1; }
    __syncthreads();
    if (tid == 0) {
        float t0 = 0.0f, t1 = 0.0f;
        #pragma unroll
        for (int i = 0; i < 16; ++i) { t0 += w0[i]; t1 += w1[i]; }
        const float inv = 1.0f / (float)BN_;
        out[0] = fmaxf(t0 * inv, t1 * inv);
    }
}

extern "C" void kernel_launch(void* const* d_in, const int* in_sizes, int n_in,
                              void* d_out, int out_size, void* d_ws, size_t ws_size,
                              hipStream_t stream)
{
    const float* x = (const float*)d_in[0];
    const float* y = (const float*)d_in[1];
    float* out = (float*)d_out;

    float4*   pk   = (float4*)d_ws;                    // 2*BN float4
    unsigned* mins = (unsigned*)(pk + 2 * BN_);        // 2*BN uint

    pack_kernel<<<2 * BN_ / TPB, TPB, 0, stream>>>(x, y, pk, mins);

    dim3 grid(N_ / QS, N_ / (PT * TPB), 2 * B_);       // 64 x 2 x 8 = 1024
    chamfer_kernel<<<grid, TPB, 0, stream>>>(pk, mins);

    finalize_kernel<<<1, 1024, 0, stream>>>(mins, out);
}